// Round 1
// baseline (701.364 us; speedup 1.0000x reference)
//
#include <hip/hip_runtime.h>

// HDC token encoder: out[b,i,d] = item_memory[token_ids[b,i]][(d - i) mod D] * 0.01f
// B=8, S=2048, V=256, D=10000. Norm of every ±1 row is exactly 100, so the
// L2-normalize is a constant scale (bit-exact vs reference).

#define B_ 8
#define S_ 2048
#define V_ 256
#define D_ 10000

__global__ __launch_bounds__(256) void hdc_encode(
    const int* __restrict__ token_ids,
    const float* __restrict__ item_memory,
    float* __restrict__ out)
{
    const int row = blockIdx.x;          // 0 .. B*S-1
    const int i   = row % S_;            // position within sequence -> shift amount
    const int tok = token_ids[row];

    const float* __restrict__ src = item_memory + (long)tok * D_;
    float*       __restrict__ dst = out + (long)row * D_;

    const float scale = 0.01f;           // 1/sqrt(D) exactly

    // D/4 = 2500 float4 chunks per row; dst row base is 16B aligned (40000 % 16 == 0)
    for (int c = threadIdx.x; c < D_ / 4; c += 256) {
        int s0 = 4 * c - i;
        if (s0 < 0) s0 += D_;
        int s1 = s0 + 1; if (s1 >= D_) s1 -= D_;
        int s2 = s0 + 2; if (s2 >= D_) s2 -= D_;
        int s3 = s0 + 3; if (s3 >= D_) s3 -= D_;

        float4 v;
        v.x = src[s0] * scale;
        v.y = src[s1] * scale;
        v.z = src[s2] * scale;
        v.w = src[s3] * scale;
        reinterpret_cast<float4*>(dst)[c] = v;
    }
}

extern "C" void kernel_launch(void* const* d_in, const int* in_sizes, int n_in,
                              void* d_out, int out_size, void* d_ws, size_t ws_size,
                              hipStream_t stream)
{
    const int*   token_ids   = (const int*)d_in[0];
    const float* item_memory = (const float*)d_in[1];
    float*       out         = (float*)d_out;

    hdc_encode<<<dim3(B_ * S_), dim3(256), 0, stream>>>(token_ids, item_memory, out);
}